// Round 11
// baseline (194.031 us; speedup 1.0000x reference)
//
#include <hip/hip_runtime.h>
#include <math.h>

#define NB   4
#define NSEQ 8192
#define CDIM 64
#define M    2048
#define NW   7
#define NBLK2 40     // sub-blocks (QT,ci) per window: 4*1+4*2+4*3+4*4 (128-row q-tiles)

typedef _Float16 half8 __attribute__((ext_vector_type(8)));
typedef __fp16 fp16x2 __attribute__((ext_vector_type(2)));   // native cvt_pkrtz type
typedef float f32x4 __attribute__((ext_vector_type(4)));
typedef unsigned short u16x4 __attribute__((ext_vector_type(4)));

#if defined(__has_builtin) && __has_builtin(__builtin_amdgcn_exp2f)
#define EXP2(x) __builtin_amdgcn_exp2f(x)
#else
#define EXP2(x) __expf((x) * 0.69314718056f)
#endif

// Q pre-scale: 1/sqrt(64) * log2(e) folded into Qg so attn uses raw exp2
#define QSCALE 0.1803368801111204f
// exp bias: p = exp2(s' - PBIAS) keeps P under f16 max; scales P and l by
// 2^-PBIAS uniformly -> O invariant, constant lse shift cancels in mix.
#define PBIAS 4.0f

// LDS (20480 B total -> 5 blocks/CU at launch_bounds(256,5)):
//   [0,8192):      K dbuf, 2 x 32 rows x 128B, R9 XOR swizzle (conflict-free b128)
//   [8192,16384):  Vt dbuf, 2 x 64 rows x 64B, pair-packed pi(k)=(k,k+16),
//                  chunk-XOR c ^= (d&3)^((d>>2)&3)  (balanced b128 reads)
//   [16384,20480): Ps, 64 rows x 64B, same pair-pack + chunk-XOR
#define K_OFF   0
#define VT_OFF  8192
#define PS_OFF  16384

__device__ __forceinline__ int win_base(int w) {
    return (w < 4) ? (w << 11) : ((w < 6) ? ((w - 4) << 12) : 0);
}
__device__ __forceinline__ int win_stride(int w) {
    return (w < 4) ? 1 : ((w < 6) ? 2 : 4);
}

// ---------------- kernel 1: QKV projection, f16 outputs -------------------
// block = 64 (1 wave): lane owns output column; W columns live in registers
// (192 VGPRs -> needs the 512-VGPR budget of launch_bounds(64,1); capping
// lower forces catastrophic scratch spills - measured 377MB FETCH in R3).
__global__ __launch_bounds__(64, 1) void qkv_proj(
        const float* __restrict__ x,
        const float* __restrict__ Wq, const float* __restrict__ Wk,
        const float* __restrict__ Wv,
        _Float16* __restrict__ Qg, _Float16* __restrict__ Kg,
        _Float16* __restrict__ Vg) {
    __shared__ __align__(16) float xs[32][64];
    const int lane = threadIdx.x;
    const long rowbase = (long)blockIdx.x * 32;

    float wq[64], wk[64], wv[64];
#pragma unroll
    for (int i = 0; i < 64; ++i) {
        wq[i] = Wq[i * 64 + lane];
        wk[i] = Wk[i * 64 + lane];
        wv[i] = Wv[i * 64 + lane];
    }
#pragma unroll
    for (int i = 0; i < 8; ++i) {
        int idx = lane + i * 64;            // 512 float4 chunks: 32 rows x 16
        int r = idx >> 4, ch = idx & 15;
        *(float4*)&xs[r][ch * 4] = *(const float4*)&x[(rowbase + r) * 64 + ch * 4];
    }
    __syncthreads();
    for (int r = 0; r < 32; ++r) {
        float aq = 0.f, ak = 0.f, av = 0.f;
#pragma unroll
        for (int i = 0; i < 64; i += 4) {
            float4 xv = *(const float4*)&xs[r][i];
            aq += xv.x * wq[i] + xv.y * wq[i + 1] + xv.z * wq[i + 2] + xv.w * wq[i + 3];
            ak += xv.x * wk[i] + xv.y * wk[i + 1] + xv.z * wk[i + 2] + xv.w * wk[i + 3];
            av += xv.x * wv[i] + xv.y * wv[i + 1] + xv.z * wv[i + 2] + xv.w * wv[i + 3];
        }
        long o = (rowbase + r) * 64 + lane;
        Qg[o] = (_Float16)(aq * QSCALE);
        Kg[o] = (_Float16)ak;
        Vg[o] = (_Float16)av;
    }
}

// ---------------- kernel 2: flash attention, 128q tile x 32k steps --------
// block = (b, w, QT, ci): q-tile 128 rows (wave owns strips 16wid and
// 64+16wid), k-steps of 32. K/Vt frags read from LDS ONCE per step, reused
// by both strips (halves the R9 frag duplication). Same barrier-per-cell
// rate as R9 (R10's doubling avoided). Wave-private Ps rows shared by the
// strips sequentially. Heavy-first dispatch. 1 barrier/step.
__global__ __launch_bounds__(256, 5) void attn(
        const _Float16* __restrict__ Qg, const _Float16* __restrict__ Kg,
        const _Float16* __restrict__ Vg,
        _Float16* __restrict__ Op, float* __restrict__ LSEp) {
    __shared__ __align__(16) char smem[20480];

    // decode (QT, ci) from reversed blockIdx.x in [0,40): heavy groups first
    int id = 39 - (int)blockIdx.x;
    int QT, ci;
    if (id < 4)       { QT = id;              ci = 0; }
    else if (id < 12) { int r = id - 4;  QT = 4  + (r >> 1); ci = r & 1; }
    else if (id < 24) { int r = id - 12; int q3 = r / 3; QT = 8 + q3; ci = r - 3 * q3; }
    else              { int r = id - 24; QT = 12 + (r >> 2); ci = r & 3; }
    const int w = blockIdx.y, b = blockIdx.z;
    const int base = win_base(w), stride = win_stride(w);
    const int g = QT >> 2;
    const int cb = 2 * g * (g + 1) + (QT & 3) * (g + 1);
    const int outblk = (b * NW + w) * NBLK2 + cb + ci;
    const int kt0 = ci * 16;                 // 32-col steps
    const int ktmax = 4 * QT + 4;
    const int kt1 = (kt0 + 16 < ktmax) ? kt0 + 16 : ktmax;

    const _Float16* Qb = Qg + (size_t)b * NSEQ * 64;
    const _Float16* Kb = Kg + (size_t)b * NSEQ * 64;
    const _Float16* Vb = Vg + (size_t)b * NSEQ * 64;

    const int t = threadIdx.x;
    const int wid = t >> 6, lane = t & 63, l15 = lane & 15, quad = lane >> 4;

    // K staging: thread stages row sr (0..31), 16B chunk sch (R9 swizzle)
    const int sr = t >> 3, sch = t & 7;
    // V staging: thread (c4 = cols 4c4.., kq = k-pair row); per-wave lanes
    // have consecutive c4 -> coalesced 128B global row reads
    const int c4 = t & 15, kq = t >> 4;      // kq in 0..15
    const int vd0 = 4 * c4;

    // Q A-frags for both strips, load once (A[m=l15][k=quad*8+j])
    const size_t qr0 = (size_t)(base + stride * (QT * 128 + 16 * wid + l15)) * 64;
    const size_t qr1 = (size_t)(base + stride * (QT * 128 + 64 + 16 * wid + l15)) * 64;
    const half8 qa00 = *(const half8*)(Qb + qr0 + quad * 8);
    const half8 qa01 = *(const half8*)(Qb + qr0 + 32 + quad * 8);
    const half8 qa10 = *(const half8*)(Qb + qr1 + quad * 8);
    const half8 qa11 = *(const half8*)(Qb + qr1 + 32 + quad * 8);

    f32x4 oacc0[4], oacc1[4];
    float l_[8];
#pragma unroll
    for (int ns = 0; ns < 4; ++ns) {
        oacc0[ns] = (f32x4){0.f, 0.f, 0.f, 0.f};
        oacc1[ns] = (f32x4){0.f, 0.f, 0.f, 0.f};
    }
#pragma unroll
    for (int j = 0; j < 8; ++j) l_[j] = 0.f;

    half8 pk;
    u16x4 pv0, pv1;

    // ---- prologue: stage step kt0 into buffer 0 ----
    {
        const size_t ka = (size_t)(base + stride * (kt0 * 32 + sr)) * 64 + sch * 8;
        pk = *(const half8*)(Kb + ka);
        const size_t va = (size_t)(base + stride * (kt0 * 32 + kq)) * 64 + vd0;
        pv0 = *(const u16x4*)(Vb + va);
        pv1 = *(const u16x4*)(Vb + va + (size_t)stride * 16 * 64);
        char* Kd = smem + K_OFF;
        char* Vd = smem + VT_OFF;
        *(half8*)(Kd + sr * 128 + ((sch ^ (sr & 7)) * 16)) = pk;
#pragma unroll
        for (int i = 0; i < 4; ++i) {
            int d = vd0 + i;
            unsigned int pkw = (unsigned int)pv0[i] | ((unsigned int)pv1[i] << 16);
            int ch = ((kq >> 2) ^ (d & 3) ^ ((d >> 2) & 3)) & 3;
            *(unsigned int*)(Vd + d * 64 + ch * 16 + (kq & 3) * 4) = pkw;
        }
    }

    int cur = 0;
    for (int kt = kt0; kt < kt1; ++kt) {
        __syncthreads();   // buf[cur] visible; all reads of buf[cur^1] done
        const bool pf = (kt + 1 < kt1);
        if (pf) {   // prefetch next step (consumed at end of this iteration)
            const size_t ka = (size_t)(base + stride * ((kt + 1) * 32 + sr)) * 64 + sch * 8;
            pk = *(const half8*)(Kb + ka);
            const size_t va = (size_t)(base + stride * ((kt + 1) * 32 + kq)) * 64 + vd0;
            pv0 = *(const u16x4*)(Vb + va);
            pv1 = *(const u16x4*)(Vb + va + (size_t)stride * 16 * 64);
        }

        const char* Kd = smem + K_OFF + cur * 4096;
        const char* Vd = smem + VT_OFF + cur * 4096;
        char* PsB = smem + PS_OFF;

        // ---- QK^T: K B-frags read ONCE, used by both strips ----
        half8 kb[2][2];
#pragma unroll
        for (int ns = 0; ns < 2; ++ns) {
            const int krow = ns * 16 + l15, swk = krow & 7;
            kb[ns][0] = *(const half8*)(Kd + krow * 128 + ((quad ^ swk) * 16));
            kb[ns][1] = *(const half8*)(Kd + krow * 128 + (((quad + 4) ^ swk) * 16));
        }
        f32x4 sa0[2], sa1[2];
#pragma unroll
        for (int ns = 0; ns < 2; ++ns) {
            f32x4 c0 = (f32x4){0.f, 0.f, 0.f, 0.f};
            c0 = __builtin_amdgcn_mfma_f32_16x16x32_f16(qa00, kb[ns][0], c0, 0, 0, 0);
            c0 = __builtin_amdgcn_mfma_f32_16x16x32_f16(qa01, kb[ns][1], c0, 0, 0, 0);
            sa0[ns] = c0;
            f32x4 c1 = (f32x4){0.f, 0.f, 0.f, 0.f};
            c1 = __builtin_amdgcn_mfma_f32_16x16x32_f16(qa10, kb[ns][0], c1, 0, 0, 0);
            c1 = __builtin_amdgcn_mfma_f32_16x16x32_f16(qa11, kb[ns][1], c1, 0, 0, 0);
            sa1[ns] = c1;
        }
        if (kt >= 4 * QT) {   // causal region (last 4 steps of the tile)
            const int colb = kt * 32 + l15;
            const int row0 = QT * 128 + 16 * wid + quad * 4;
#pragma unroll
            for (int ns = 0; ns < 2; ++ns)
#pragma unroll
                for (int j = 0; j < 4; ++j) {
                    if (colb + ns * 16 > row0 + j)      sa0[ns][j] = -1e30f;
                    if (colb + ns * 16 > row0 + 64 + j) sa1[ns][j] = -1e30f;
                }
        }

        // ---- Vt B-frags read ONCE, reused by both strips' PV ----
        half8 vb[4];
#pragma unroll
        for (int ns = 0; ns < 4; ++ns) {
            const int d = ns * 16 + l15;
            const int ch = (quad ^ (d & 3) ^ ((d >> 2) & 3)) & 3;
            vb[ns] = *(const half8*)(Vd + d * 64 + ch * 16);
        }

        // ---- strip0: exp2 + P write (pair-pack + chunk-XOR) + PV ----
#pragma unroll
        for (int j = 0; j < 4; ++j) {
            const int q = 16 * wid + quad * 4 + j;
            float p0 = EXP2(sa0[0][j] - PBIAS);
            float p1 = EXP2(sa0[1][j] - PBIAS);
            l_[j] += p0 + p1;
            union { fp16x2 h; unsigned int u; } pw;
            pw.h = __builtin_amdgcn_cvt_pkrtz(p0, p1);
            const int ch = ((l15 >> 2) ^ (q & 3) ^ ((q >> 2) & 3)) & 3;
            *(unsigned int*)(PsB + q * 64 + ch * 16 + (l15 & 3) * 4) = pw.u;
        }
        {
            const int qp = 16 * wid + l15;
            const int ch = (quad ^ (qp & 3) ^ ((qp >> 2) & 3)) & 3;
            half8 pa = *(const half8*)(PsB + qp * 64 + ch * 16);
#pragma unroll
            for (int ns = 0; ns < 4; ++ns)
                oacc0[ns] = __builtin_amdgcn_mfma_f32_16x16x32_f16(pa, vb[ns], oacc0[ns], 0, 0, 0);
        }

        // ---- strip1: same Ps rows (same-wave DS ordering => safe) ----
#pragma unroll
        for (int j = 0; j < 4; ++j) {
            const int q = 16 * wid + quad * 4 + j;
            float p0 = EXP2(sa1[0][j] - PBIAS);
            float p1 = EXP2(sa1[1][j] - PBIAS);
            l_[4 + j] += p0 + p1;
            union { fp16x2 h; unsigned int u; } pw;
            pw.h = __builtin_amdgcn_cvt_pkrtz(p0, p1);
            const int ch = ((l15 >> 2) ^ (q & 3) ^ ((q >> 2) & 3)) & 3;
            *(unsigned int*)(PsB + q * 64 + ch * 16 + (l15 & 3) * 4) = pw.u;
        }
        {
            const int qp = 16 * wid + l15;
            const int ch = (quad ^ (qp & 3) ^ ((qp >> 2) & 3)) & 3;
            half8 pa = *(const half8*)(PsB + qp * 64 + ch * 16);
#pragma unroll
            for (int ns = 0; ns < 4; ++ns)
                oacc1[ns] = __builtin_amdgcn_mfma_f32_16x16x32_f16(pa, vb[ns], oacc1[ns], 0, 0, 0);
        }

        // ---- write prefetched step into the other buffer ----
        if (pf) {
            char* Kn = smem + K_OFF + (cur ^ 1) * 4096;
            char* Vn = smem + VT_OFF + (cur ^ 1) * 4096;
            *(half8*)(Kn + sr * 128 + ((sch ^ (sr & 7)) * 16)) = pk;
#pragma unroll
            for (int i = 0; i < 4; ++i) {
                int d = vd0 + i;
                unsigned int pkw = (unsigned int)pv0[i] | ((unsigned int)pv1[i] << 16);
                int ch = ((kq >> 2) ^ (d & 3) ^ ((d >> 2) & 3)) & 3;
                *(unsigned int*)(Vn + d * 64 + ch * 16 + (kq & 3) * 4) = pkw;
            }
        }
        cur ^= 1;
    }

    // ---- epilogue: reduce l, store O (f16) and lse per strip ----
#pragma unroll
    for (int j = 0; j < 8; ++j) {
        float s = l_[j];
        s += __shfl_xor(s, 1, 16);
        s += __shfl_xor(s, 2, 16);
        s += __shfl_xor(s, 4, 16);
        s += __shfl_xor(s, 8, 16);
        l_[j] = s;
    }
    const int qrow0 = 16 * wid + quad * 4;
    if (l15 == 0) {
#pragma unroll
        for (int j = 0; j < 4; ++j) {
            LSEp[(size_t)outblk * 128 + qrow0 + j]      = __logf(l_[j]);
            LSEp[(size_t)outblk * 128 + 64 + qrow0 + j] = __logf(l_[4 + j]);
        }
    }
#pragma unroll
    for (int j = 0; j < 4; ++j) {
        const float inv0 = 1.0f / l_[j];
        const float inv1 = 1.0f / l_[4 + j];
        const size_t r0off = ((size_t)outblk * 128 + qrow0 + j) * 64 + l15;
        const size_t r1off = ((size_t)outblk * 128 + 64 + qrow0 + j) * 64 + l15;
#pragma unroll
        for (int ns = 0; ns < 4; ++ns) {
            Op[r0off + ns * 16] = (_Float16)(oacc0[ns][j] * inv0);
            Op[r1off + ns * 16] = (_Float16)(oacc1[ns][j] * inv1);
        }
    }
}

// ---------------- kernel 3: merge all (window, chunk) partials ------------
typedef _Float16 half8v __attribute__((ext_vector_type(8)));
__global__ __launch_bounds__(256) void mix_out(
        const _Float16* __restrict__ Op, const float* __restrict__ LSEp,
        float* __restrict__ out) {
    int gid = blockIdx.x * 256 + threadIdx.x;   // [0, 4*8192*8)
    int f8 = gid & 7;
    int tpos = (gid >> 3) & (NSEQ - 1);
    int b = gid >> 16;

    int idxs[12];
    float lse[12];
    int nref = 0;
    {   // window of stride 1
        int w = tpos >> 11, j = tpos & (M - 1);
        int QT = j >> 7, gg = QT >> 2, q = j & 127;
        int cbase = 2 * gg * (gg + 1) + (QT & 3) * (gg + 1);
        int bb = ((b * NW + w) * NBLK2 + cbase) * 128 + q;
        int cmax = j >> 9;
        for (int c = 0; c <= cmax; ++c) { idxs[nref] = bb + c * 128; lse[nref] = LSEp[idxs[nref]]; ++nref; }
    }
    if (!(tpos & 1)) {   // stride 2
        int w = 4 + (tpos >> 12), j = (tpos & 4095) >> 1;
        int QT = j >> 7, gg = QT >> 2, q = j & 127;
        int cbase = 2 * gg * (gg + 1) + (QT & 3) * (gg + 1);
        int bb = ((b * NW + w) * NBLK2 + cbase) * 128 + q;
        int cmax = j >> 9;
        for (int c = 0; c <= cmax; ++c) { idxs[nref] = bb + c * 128; lse[nref] = LSEp[idxs[nref]]; ++nref; }
    }
    if (!(tpos & 3)) {   // stride 4
        int j = tpos >> 2;
        int QT = j >> 7, gg = QT >> 2, q = j & 127;
        int cbase = 2 * gg * (gg + 1) + (QT & 3) * (gg + 1);
        int bb = ((b * NW + 6) * NBLK2 + cbase) * 128 + q;
        int cmax = j >> 9;
        for (int c = 0; c <= cmax; ++c) { idxs[nref] = bb + c * 128; lse[nref] = LSEp[idxs[nref]]; ++nref; }
    }

    float Mx = -1e30f;
    for (int i = 0; i < nref; ++i) Mx = fmaxf(Mx, lse[i]);
    float acc[8];
#pragma unroll
    for (int k = 0; k < 8; ++k) acc[k] = 0.f;
    float wsum = 0.f;
    for (int i = 0; i < nref; ++i) {
        float a = __expf(lse[i] - Mx);
        wsum += a;
        half8v v = *(const half8v*)(Op + (size_t)idxs[i] * 64 + f8 * 8);
#pragma unroll
        for (int k = 0; k < 8; ++k) acc[k] += a * (float)v[k];
    }
    float inv = 1.0f / wsum;
    size_t o = ((size_t)b * NSEQ + tpos) * 64 + f8 * 8;
    float4 r0 = make_float4(acc[0] * inv, acc[1] * inv, acc[2] * inv, acc[3] * inv);
    float4 r1 = make_float4(acc[4] * inv, acc[5] * inv, acc[6] * inv, acc[7] * inv);
    *(float4*)&out[o] = r0;
    *(float4*)&out[o + 4] = r1;
}

extern "C" void kernel_launch(void* const* d_in, const int* in_sizes, int n_in,
                              void* d_out, int out_size, void* d_ws, size_t ws_size,
                              hipStream_t stream) {
    const float* x  = (const float*)d_in[0];
    const float* Wq = (const float*)d_in[1];
    const float* Wk = (const float*)d_in[2];
    const float* Wv = (const float*)d_in[3];
    float* out = (float*)d_out;

    const size_t QN = (size_t)NB * NSEQ * CDIM;     // 2,097,152
    _Float16* Qg = (_Float16*)d_ws;
    _Float16* Kg = Qg + QN;
    _Float16* Vg = Kg + QN;
    _Float16* Op = Vg + QN;                         // [b][w][40][128][64] f16
    float* LSEp  = (float*)(Op + (size_t)NB * NW * NBLK2 * 128 * 64);

    qkv_proj<<<NB * NSEQ / 32, 64, 0, stream>>>(x, Wq, Wk, Wv, Qg, Kg, Vg);
    attn<<<dim3(NBLK2, NW, NB), 256, 0, stream>>>(Qg, Kg, Vg, Op, LSEp);
    mix_out<<<(NB * NSEQ * 8) / 256, 256, 0, stream>>>(Op, LSEp, out);
}

// Round 12
// 143.058 us; speedup vs baseline: 1.3563x; 1.3563x over previous
//
#include <hip/hip_runtime.h>
#include <math.h>

#define NB   4
#define NSEQ 8192
#define CDIM 64
#define M    2048
#define NW   7
#define NBLK2 40     // sub-blocks (QT,ci) per window: 4*1+4*2+4*3+4*4 (128-row q-tiles)

typedef _Float16 half8 __attribute__((ext_vector_type(8)));
typedef __fp16 fp16x2 __attribute__((ext_vector_type(2)));   // native cvt_pkrtz type
typedef float f32x4 __attribute__((ext_vector_type(4)));
typedef unsigned short u16x4 __attribute__((ext_vector_type(4)));

#if defined(__has_builtin) && __has_builtin(__builtin_amdgcn_exp2f)
#define EXP2(x) __builtin_amdgcn_exp2f(x)
#else
#define EXP2(x) __expf((x) * 0.69314718056f)
#endif

// Q pre-scale: 1/sqrt(64) * log2(e) folded into Qg so attn uses raw exp2
#define QSCALE 0.1803368801111204f
// exp bias: p = exp2(s' - PBIAS) keeps P under f16 max; scales P and l by
// 2^-PBIAS uniformly -> O invariant, constant lse shift cancels in mix.
#define PBIAS 4.0f

// LDS (20480 B total):
//   [0,8192):      K dbuf, 2 x 32 rows x 128B, R9 XOR swizzle (conflict-free b128)
//   [8192,16384):  Vt dbuf, 2 x 64 rows x 64B, pair-packed pi(k)=(k,k+16),
//                  chunk-XOR c ^= (d&3)^((d>>2)&3)  (balanced b128 reads)
//   [16384,20480): Ps, 64 rows x 64B, same pair-pack + chunk-XOR
#define K_OFF   0
#define VT_OFF  8192
#define PS_OFF  16384

__device__ __forceinline__ int win_base(int w) {
    return (w < 4) ? (w << 11) : ((w < 6) ? ((w - 4) << 12) : 0);
}
__device__ __forceinline__ int win_stride(int w) {
    return (w < 4) ? 1 : ((w < 6) ? 2 : 4);
}

// ---------------- kernel 1: QKV projection, f16 outputs -------------------
// block = 64 (1 wave): lane owns output column; W columns live in registers
// (192 VGPRs -> needs the 512-VGPR budget of launch_bounds(64,1); capping
// lower forces catastrophic scratch spills - measured 377MB FETCH in R3).
__global__ __launch_bounds__(64, 1) void qkv_proj(
        const float* __restrict__ x,
        const float* __restrict__ Wq, const float* __restrict__ Wk,
        const float* __restrict__ Wv,
        _Float16* __restrict__ Qg, _Float16* __restrict__ Kg,
        _Float16* __restrict__ Vg) {
    __shared__ __align__(16) float xs[32][64];
    const int lane = threadIdx.x;
    const long rowbase = (long)blockIdx.x * 32;

    float wq[64], wk[64], wv[64];
#pragma unroll
    for (int i = 0; i < 64; ++i) {
        wq[i] = Wq[i * 64 + lane];
        wk[i] = Wk[i * 64 + lane];
        wv[i] = Wv[i * 64 + lane];
    }
#pragma unroll
    for (int i = 0; i < 8; ++i) {
        int idx = lane + i * 64;            // 512 float4 chunks: 32 rows x 16
        int r = idx >> 4, ch = idx & 15;
        *(float4*)&xs[r][ch * 4] = *(const float4*)&x[(rowbase + r) * 64 + ch * 4];
    }
    __syncthreads();
    for (int r = 0; r < 32; ++r) {
        float aq = 0.f, ak = 0.f, av = 0.f;
#pragma unroll
        for (int i = 0; i < 64; i += 4) {
            float4 xv = *(const float4*)&xs[r][i];
            aq += xv.x * wq[i] + xv.y * wq[i + 1] + xv.z * wq[i + 2] + xv.w * wq[i + 3];
            ak += xv.x * wk[i] + xv.y * wk[i + 1] + xv.z * wk[i + 2] + xv.w * wk[i + 3];
            av += xv.x * wv[i] + xv.y * wv[i + 1] + xv.z * wv[i + 2] + xv.w * wv[i + 3];
        }
        long o = (rowbase + r) * 64 + lane;
        Qg[o] = (_Float16)(aq * QSCALE);
        Kg[o] = (_Float16)ak;
        Vg[o] = (_Float16)av;
    }
}

// ---------------- kernel 2: flash attention, 128q tile x 32k steps --------
// Identical to R11 except __launch_bounds__(256, 4): R11's (256,5) capped
// VGPRs at ~102 < the ~110 live set -> catastrophic scratch spills (FETCH
// 133MB, WRITE 112MB, VGPR_Count=48). Cap 128 fits the footprint; occupancy
// is then VGPR-pool-limited to ~4 blocks/CU (same as R9) with ~21% less LDS
// traffic per cell and the same barrier rate.
__global__ __launch_bounds__(256, 4) void attn(
        const _Float16* __restrict__ Qg, const _Float16* __restrict__ Kg,
        const _Float16* __restrict__ Vg,
        _Float16* __restrict__ Op, float* __restrict__ LSEp) {
    __shared__ __align__(16) char smem[20480];

    // decode (QT, ci) from reversed blockIdx.x in [0,40): heavy groups first
    int id = 39 - (int)blockIdx.x;
    int QT, ci;
    if (id < 4)       { QT = id;              ci = 0; }
    else if (id < 12) { int r = id - 4;  QT = 4  + (r >> 1); ci = r & 1; }
    else if (id < 24) { int r = id - 12; int q3 = r / 3; QT = 8 + q3; ci = r - 3 * q3; }
    else              { int r = id - 24; QT = 12 + (r >> 2); ci = r & 3; }
    const int w = blockIdx.y, b = blockIdx.z;
    const int base = win_base(w), stride = win_stride(w);
    const int g = QT >> 2;
    const int cb = 2 * g * (g + 1) + (QT & 3) * (g + 1);
    const int outblk = (b * NW + w) * NBLK2 + cb + ci;
    const int kt0 = ci * 16;                 // 32-col steps
    const int ktmax = 4 * QT + 4;
    const int kt1 = (kt0 + 16 < ktmax) ? kt0 + 16 : ktmax;

    const _Float16* Qb = Qg + (size_t)b * NSEQ * 64;
    const _Float16* Kb = Kg + (size_t)b * NSEQ * 64;
    const _Float16* Vb = Vg + (size_t)b * NSEQ * 64;

    const int t = threadIdx.x;
    const int wid = t >> 6, lane = t & 63, l15 = lane & 15, quad = lane >> 4;

    // K staging: thread stages row sr (0..31), 16B chunk sch (R9 swizzle)
    const int sr = t >> 3, sch = t & 7;
    // V staging: thread (c4 = cols 4c4.., kq = k-pair row); per-wave lanes
    // have consecutive c4 -> coalesced 128B global row reads
    const int c4 = t & 15, kq = t >> 4;      // kq in 0..15
    const int vd0 = 4 * c4;

    // Q A-frags for both strips, load once (A[m=l15][k=quad*8+j])
    const size_t qr0 = (size_t)(base + stride * (QT * 128 + 16 * wid + l15)) * 64;
    const size_t qr1 = (size_t)(base + stride * (QT * 128 + 64 + 16 * wid + l15)) * 64;
    const half8 qa00 = *(const half8*)(Qb + qr0 + quad * 8);
    const half8 qa01 = *(const half8*)(Qb + qr0 + 32 + quad * 8);
    const half8 qa10 = *(const half8*)(Qb + qr1 + quad * 8);
    const half8 qa11 = *(const half8*)(Qb + qr1 + 32 + quad * 8);

    f32x4 oacc0[4], oacc1[4];
    float l_[8];
#pragma unroll
    for (int ns = 0; ns < 4; ++ns) {
        oacc0[ns] = (f32x4){0.f, 0.f, 0.f, 0.f};
        oacc1[ns] = (f32x4){0.f, 0.f, 0.f, 0.f};
    }
#pragma unroll
    for (int j = 0; j < 8; ++j) l_[j] = 0.f;

    half8 pk;
    u16x4 pv0, pv1;

    // ---- prologue: stage step kt0 into buffer 0 ----
    {
        const size_t ka = (size_t)(base + stride * (kt0 * 32 + sr)) * 64 + sch * 8;
        pk = *(const half8*)(Kb + ka);
        const size_t va = (size_t)(base + stride * (kt0 * 32 + kq)) * 64 + vd0;
        pv0 = *(const u16x4*)(Vb + va);
        pv1 = *(const u16x4*)(Vb + va + (size_t)stride * 16 * 64);
        char* Kd = smem + K_OFF;
        char* Vd = smem + VT_OFF;
        *(half8*)(Kd + sr * 128 + ((sch ^ (sr & 7)) * 16)) = pk;
#pragma unroll
        for (int i = 0; i < 4; ++i) {
            int d = vd0 + i;
            unsigned int pkw = (unsigned int)pv0[i] | ((unsigned int)pv1[i] << 16);
            int ch = ((kq >> 2) ^ (d & 3) ^ ((d >> 2) & 3)) & 3;
            *(unsigned int*)(Vd + d * 64 + ch * 16 + (kq & 3) * 4) = pkw;
        }
    }

    int cur = 0;
    for (int kt = kt0; kt < kt1; ++kt) {
        __syncthreads();   // buf[cur] visible; all reads of buf[cur^1] done
        const bool pf = (kt + 1 < kt1);
        if (pf) {   // prefetch next step (consumed at end of this iteration)
            const size_t ka = (size_t)(base + stride * ((kt + 1) * 32 + sr)) * 64 + sch * 8;
            pk = *(const half8*)(Kb + ka);
            const size_t va = (size_t)(base + stride * ((kt + 1) * 32 + kq)) * 64 + vd0;
            pv0 = *(const u16x4*)(Vb + va);
            pv1 = *(const u16x4*)(Vb + va + (size_t)stride * 16 * 64);
        }

        const char* Kd = smem + K_OFF + cur * 4096;
        const char* Vd = smem + VT_OFF + cur * 4096;
        char* PsB = smem + PS_OFF;

        // ---- QK^T: K B-frags read ONCE, used by both strips ----
        half8 kb[2][2];
#pragma unroll
        for (int ns = 0; ns < 2; ++ns) {
            const int krow = ns * 16 + l15, swk = krow & 7;
            kb[ns][0] = *(const half8*)(Kd + krow * 128 + ((quad ^ swk) * 16));
            kb[ns][1] = *(const half8*)(Kd + krow * 128 + (((quad + 4) ^ swk) * 16));
        }
        f32x4 sa0[2], sa1[2];
#pragma unroll
        for (int ns = 0; ns < 2; ++ns) {
            f32x4 c0 = (f32x4){0.f, 0.f, 0.f, 0.f};
            c0 = __builtin_amdgcn_mfma_f32_16x16x32_f16(qa00, kb[ns][0], c0, 0, 0, 0);
            c0 = __builtin_amdgcn_mfma_f32_16x16x32_f16(qa01, kb[ns][1], c0, 0, 0, 0);
            sa0[ns] = c0;
            f32x4 c1 = (f32x4){0.f, 0.f, 0.f, 0.f};
            c1 = __builtin_amdgcn_mfma_f32_16x16x32_f16(qa10, kb[ns][0], c1, 0, 0, 0);
            c1 = __builtin_amdgcn_mfma_f32_16x16x32_f16(qa11, kb[ns][1], c1, 0, 0, 0);
            sa1[ns] = c1;
        }
        if (kt >= 4 * QT) {   // causal region (last 4 steps of the tile)
            const int colb = kt * 32 + l15;
            const int row0 = QT * 128 + 16 * wid + quad * 4;
#pragma unroll
            for (int ns = 0; ns < 2; ++ns)
#pragma unroll
                for (int j = 0; j < 4; ++j) {
                    if (colb + ns * 16 > row0 + j)      sa0[ns][j] = -1e30f;
                    if (colb + ns * 16 > row0 + 64 + j) sa1[ns][j] = -1e30f;
                }
        }

        // ---- Vt B-frags read ONCE, reused by both strips' PV ----
        half8 vb[4];
#pragma unroll
        for (int ns = 0; ns < 4; ++ns) {
            const int d = ns * 16 + l15;
            const int ch = (quad ^ (d & 3) ^ ((d >> 2) & 3)) & 3;
            vb[ns] = *(const half8*)(Vd + d * 64 + ch * 16);
        }

        // ---- strip0: exp2 + P write (pair-pack + chunk-XOR) + PV ----
#pragma unroll
        for (int j = 0; j < 4; ++j) {
            const int q = 16 * wid + quad * 4 + j;
            float p0 = EXP2(sa0[0][j] - PBIAS);
            float p1 = EXP2(sa0[1][j] - PBIAS);
            l_[j] += p0 + p1;
            union { fp16x2 h; unsigned int u; } pw;
            pw.h = __builtin_amdgcn_cvt_pkrtz(p0, p1);
            const int ch = ((l15 >> 2) ^ (q & 3) ^ ((q >> 2) & 3)) & 3;
            *(unsigned int*)(PsB + q * 64 + ch * 16 + (l15 & 3) * 4) = pw.u;
        }
        {
            const int qp = 16 * wid + l15;
            const int ch = (quad ^ (qp & 3) ^ ((qp >> 2) & 3)) & 3;
            half8 pa = *(const half8*)(PsB + qp * 64 + ch * 16);
#pragma unroll
            for (int ns = 0; ns < 4; ++ns)
                oacc0[ns] = __builtin_amdgcn_mfma_f32_16x16x32_f16(pa, vb[ns], oacc0[ns], 0, 0, 0);
        }

        // ---- strip1: same Ps rows (same-wave DS ordering => safe) ----
#pragma unroll
        for (int j = 0; j < 4; ++j) {
            const int q = 16 * wid + quad * 4 + j;
            float p0 = EXP2(sa1[0][j] - PBIAS);
            float p1 = EXP2(sa1[1][j] - PBIAS);
            l_[4 + j] += p0 + p1;
            union { fp16x2 h; unsigned int u; } pw;
            pw.h = __builtin_amdgcn_cvt_pkrtz(p0, p1);
            const int ch = ((l15 >> 2) ^ (q & 3) ^ ((q >> 2) & 3)) & 3;
            *(unsigned int*)(PsB + q * 64 + ch * 16 + (l15 & 3) * 4) = pw.u;
        }
        {
            const int qp = 16 * wid + l15;
            const int ch = (quad ^ (qp & 3) ^ ((qp >> 2) & 3)) & 3;
            half8 pa = *(const half8*)(PsB + qp * 64 + ch * 16);
#pragma unroll
            for (int ns = 0; ns < 4; ++ns)
                oacc1[ns] = __builtin_amdgcn_mfma_f32_16x16x32_f16(pa, vb[ns], oacc1[ns], 0, 0, 0);
        }

        // ---- write prefetched step into the other buffer ----
        if (pf) {
            char* Kn = smem + K_OFF + (cur ^ 1) * 4096;
            char* Vn = smem + VT_OFF + (cur ^ 1) * 4096;
            *(half8*)(Kn + sr * 128 + ((sch ^ (sr & 7)) * 16)) = pk;
#pragma unroll
            for (int i = 0; i < 4; ++i) {
                int d = vd0 + i;
                unsigned int pkw = (unsigned int)pv0[i] | ((unsigned int)pv1[i] << 16);
                int ch = ((kq >> 2) ^ (d & 3) ^ ((d >> 2) & 3)) & 3;
                *(unsigned int*)(Vn + d * 64 + ch * 16 + (kq & 3) * 4) = pkw;
            }
        }
        cur ^= 1;
    }

    // ---- epilogue: reduce l, store O (f16) and lse per strip ----
#pragma unroll
    for (int j = 0; j < 8; ++j) {
        float s = l_[j];
        s += __shfl_xor(s, 1, 16);
        s += __shfl_xor(s, 2, 16);
        s += __shfl_xor(s, 4, 16);
        s += __shfl_xor(s, 8, 16);
        l_[j] = s;
    }
    const int qrow0 = 16 * wid + quad * 4;
    if (l15 == 0) {
#pragma unroll
        for (int j = 0; j < 4; ++j) {
            LSEp[(size_t)outblk * 128 + qrow0 + j]      = __logf(l_[j]);
            LSEp[(size_t)outblk * 128 + 64 + qrow0 + j] = __logf(l_[4 + j]);
        }
    }
#pragma unroll
    for (int j = 0; j < 4; ++j) {
        const float inv0 = 1.0f / l_[j];
        const float inv1 = 1.0f / l_[4 + j];
        const size_t r0off = ((size_t)outblk * 128 + qrow0 + j) * 64 + l15;
        const size_t r1off = ((size_t)outblk * 128 + 64 + qrow0 + j) * 64 + l15;
#pragma unroll
        for (int ns = 0; ns < 4; ++ns) {
            Op[r0off + ns * 16] = (_Float16)(oacc0[ns][j] * inv0);
            Op[r1off + ns * 16] = (_Float16)(oacc1[ns][j] * inv1);
        }
    }
}

// ---------------- kernel 3: merge all (window, chunk) partials ------------
typedef _Float16 half8v __attribute__((ext_vector_type(8)));
__global__ __launch_bounds__(256) void mix_out(
        const _Float16* __restrict__ Op, const float* __restrict__ LSEp,
        float* __restrict__ out) {
    int gid = blockIdx.x * 256 + threadIdx.x;   // [0, 4*8192*8)
    int f8 = gid & 7;
    int tpos = (gid >> 3) & (NSEQ - 1);
    int b = gid >> 16;

    int idxs[12];
    float lse[12];
    int nref = 0;
    {   // window of stride 1
        int w = tpos >> 11, j = tpos & (M - 1);
        int QT = j >> 7, gg = QT >> 2, q = j & 127;
        int cbase = 2 * gg * (gg + 1) + (QT & 3) * (gg + 1);
        int bb = ((b * NW + w) * NBLK2 + cbase) * 128 + q;
        int cmax = j >> 9;
        for (int c = 0; c <= cmax; ++c) { idxs[nref] = bb + c * 128; lse[nref] = LSEp[idxs[nref]]; ++nref; }
    }
    if (!(tpos & 1)) {   // stride 2
        int w = 4 + (tpos >> 12), j = (tpos & 4095) >> 1;
        int QT = j >> 7, gg = QT >> 2, q = j & 127;
        int cbase = 2 * gg * (gg + 1) + (QT & 3) * (gg + 1);
        int bb = ((b * NW + w) * NBLK2 + cbase) * 128 + q;
        int cmax = j >> 9;
        for (int c = 0; c <= cmax; ++c) { idxs[nref] = bb + c * 128; lse[nref] = LSEp[idxs[nref]]; ++nref; }
    }
    if (!(tpos & 3)) {   // stride 4
        int j = tpos >> 2;
        int QT = j >> 7, gg = QT >> 2, q = j & 127;
        int cbase = 2 * gg * (gg + 1) + (QT & 3) * (gg + 1);
        int bb = ((b * NW + 6) * NBLK2 + cbase) * 128 + q;
        int cmax = j >> 9;
        for (int c = 0; c <= cmax; ++c) { idxs[nref] = bb + c * 128; lse[nref] = LSEp[idxs[nref]]; ++nref; }
    }

    float Mx = -1e30f;
    for (int i = 0; i < nref; ++i) Mx = fmaxf(Mx, lse[i]);
    float acc[8];
#pragma unroll
    for (int k = 0; k < 8; ++k) acc[k] = 0.f;
    float wsum = 0.f;
    for (int i = 0; i < nref; ++i) {
        float a = __expf(lse[i] - Mx);
        wsum += a;
        half8v v = *(const half8v*)(Op + (size_t)idxs[i] * 64 + f8 * 8);
#pragma unroll
        for (int k = 0; k < 8; ++k) acc[k] += a * (float)v[k];
    }
    float inv = 1.0f / wsum;
    size_t o = ((size_t)b * NSEQ + tpos) * 64 + f8 * 8;
    float4 r0 = make_float4(acc[0] * inv, acc[1] * inv, acc[2] * inv, acc[3] * inv);
    float4 r1 = make_float4(acc[4] * inv, acc[5] * inv, acc[6] * inv, acc[7] * inv);
    *(float4*)&out[o] = r0;
    *(float4*)&out[o + 4] = r1;
}

extern "C" void kernel_launch(void* const* d_in, const int* in_sizes, int n_in,
                              void* d_out, int out_size, void* d_ws, size_t ws_size,
                              hipStream_t stream) {
    const float* x  = (const float*)d_in[0];
    const float* Wq = (const float*)d_in[1];
    const float* Wk = (const float*)d_in[2];
    const float* Wv = (const float*)d_in[3];
    float* out = (float*)d_out;

    const size_t QN = (size_t)NB * NSEQ * CDIM;     // 2,097,152
    _Float16* Qg = (_Float16*)d_ws;
    _Float16* Kg = Qg + QN;
    _Float16* Vg = Kg + QN;
    _Float16* Op = Vg + QN;                         // [b][w][40][128][64] f16
    float* LSEp  = (float*)(Op + (size_t)NB * NW * NBLK2 * 128 * 64);

    qkv_proj<<<NB * NSEQ / 32, 64, 0, stream>>>(x, Wq, Wk, Wv, Qg, Kg, Vg);
    attn<<<dim3(NBLK2, NW, NB), 256, 0, stream>>>(Qg, Kg, Vg, Op, LSEp);
    mix_out<<<(NB * NSEQ * 8) / 256, 256, 0, stream>>>(Op, LSEp, out);
}

// Round 13
// 123.065 us; speedup vs baseline: 1.5766x; 1.1625x over previous
//
#include <hip/hip_runtime.h>
#include <math.h>

#define NB   4
#define NSEQ 8192
#define CDIM 64
#define M    2048
#define NW   7
#define NBLK2 40     // sub-blocks (QT,ci) per window: 4*1+4*2+4*3+4*4 (128-row q-tiles)

typedef _Float16 half8 __attribute__((ext_vector_type(8)));
typedef __fp16 fp16x2 __attribute__((ext_vector_type(2)));   // native cvt_pkrtz type
typedef float f32x4 __attribute__((ext_vector_type(4)));
typedef unsigned short u16x4 __attribute__((ext_vector_type(4)));

#if defined(__has_builtin) && __has_builtin(__builtin_amdgcn_exp2f)
#define EXP2(x) __builtin_amdgcn_exp2f(x)
#else
#define EXP2(x) __expf((x) * 0.69314718056f)
#endif

// Q pre-scale: 1/sqrt(64) * log2(e) folded into Wq's B-frags so attn uses raw exp2
#define QSCALE 0.1803368801111204f
// exp bias: p = exp2(s' - PBIAS) keeps P under f16 max; scales P and l by
// 2^-PBIAS uniformly -> O invariant, constant lse shift cancels in mix.
#define PBIAS 4.0f

// attn LDS (20480 B total):
//   [0,8192):      K dbuf, 2 x 32 rows x 128B, XOR swizzle (conflict-free b128)
//   [8192,16384):  Vt dbuf, 2 x 64 rows x 64B, pair-packed pi(k)=(k,k+16),
//                  chunk-XOR c ^= (d&3)^((d>>2)&3)  (balanced b128 reads)
//   [16384,20480): Ps, 64 rows x 64B, same pair-pack + chunk-XOR
#define K_OFF   0
#define VT_OFF  8192
#define PS_OFF  16384

__device__ __forceinline__ int win_base(int w) {
    return (w < 4) ? (w << 11) : ((w < 6) ? ((w - 4) << 12) : 0);
}
__device__ __forceinline__ int win_stride(int w) {
    return (w < 4) ? 1 : ((w < 6) ? 2 : 4);
}

// ---------------- kernel 1: QKV projection via MFMA, f16 outputs ----------
// 256 blocks x 256 threads (1 block/CU), 128 rows/block, 32 rows/wave.
// W held as 24 MFMA B-frags per wave (96 VGPR, one-time load+cvt); per
// 16-row m-tile: 4 global f32x4 A-loads -> cvt -> 24 MFMA -> f16 stores.
// Layout pattern copied from the end-to-end-verified attn QK MFMA:
//   A[m=l15][k=quad*8+j], B[k=quad*8+j][n=l15], C[m=quad*4+j][n=l15].
__global__ __launch_bounds__(256, 1) void qkv_proj(
        const float* __restrict__ x,
        const float* __restrict__ Wq, const float* __restrict__ Wk,
        const float* __restrict__ Wv,
        _Float16* __restrict__ Qg, _Float16* __restrict__ Kg,
        _Float16* __restrict__ Vg) {
    const int t = threadIdx.x;
    const int wid = t >> 6, lane = t & 63, l15 = lane & 15, quad = lane >> 4;

    // ---- one-time: W -> B-frags (f32 load, scale Q, cvt to f16) ----
    half8 wb[3][2][4];
#pragma unroll
    for (int m = 0; m < 3; ++m) {
        const float* Wm = (m == 0) ? Wq : ((m == 1) ? Wk : Wv);
        const float sc = (m == 0) ? QSCALE : 1.0f;
#pragma unroll
        for (int kh = 0; kh < 2; ++kh)
#pragma unroll
            for (int nt = 0; nt < 4; ++nt) {
                float f[8];
#pragma unroll
                for (int j = 0; j < 8; ++j)
                    f[j] = Wm[(kh * 32 + quad * 8 + j) * 64 + nt * 16 + l15] * sc;
                union { fp16x2 h[4]; half8 v; } u;
#pragma unroll
                for (int p = 0; p < 4; ++p)
                    u.h[p] = __builtin_amdgcn_cvt_pkrtz(f[2 * p], f[2 * p + 1]);
                wb[m][kh][nt] = u.v;
            }
    }

    const int rowbase = blockIdx.x * 128 + wid * 32;
#pragma unroll
    for (int mt = 0; mt < 2; ++mt) {
        const int r0 = rowbase + mt * 16;
        // A-frags: X rows (r0+l15), f32 -> f16
        half8 xa[2];
#pragma unroll
        for (int kh = 0; kh < 2; ++kh) {
            const float* xr = x + (size_t)(r0 + l15) * 64 + kh * 32 + quad * 8;
            const float4 a = *(const float4*)xr;
            const float4 b2 = *(const float4*)(xr + 4);
            union { fp16x2 h[4]; half8 v; } u;
            u.h[0] = __builtin_amdgcn_cvt_pkrtz(a.x, a.y);
            u.h[1] = __builtin_amdgcn_cvt_pkrtz(a.z, a.w);
            u.h[2] = __builtin_amdgcn_cvt_pkrtz(b2.x, b2.y);
            u.h[3] = __builtin_amdgcn_cvt_pkrtz(b2.z, b2.w);
            xa[kh] = u.v;
        }
#pragma unroll
        for (int m = 0; m < 3; ++m) {
            f32x4 acc[4];
#pragma unroll
            for (int nt = 0; nt < 4; ++nt) {
                acc[nt] = (f32x4){0.f, 0.f, 0.f, 0.f};
                acc[nt] = __builtin_amdgcn_mfma_f32_16x16x32_f16(xa[0], wb[m][0][nt], acc[nt], 0, 0, 0);
                acc[nt] = __builtin_amdgcn_mfma_f32_16x16x32_f16(xa[1], wb[m][1][nt], acc[nt], 0, 0, 0);
            }
            _Float16* outp = (m == 0) ? Qg : ((m == 1) ? Kg : Vg);
#pragma unroll
            for (int nt = 0; nt < 4; ++nt)
#pragma unroll
                for (int j = 0; j < 4; ++j)
                    outp[(size_t)(r0 + quad * 4 + j) * 64 + nt * 16 + l15] =
                        (_Float16)acc[nt][j];
        }
    }
}

// ---------------- kernel 2: flash attention, 128q tile x 32k steps --------
// R12-identical. (256,4): R11's (256,5) capped VGPRs below the ~110 live set
// -> catastrophic spills. K/Vt frags read once per step, reused by both
// q-strips; wave-private Ps; heavy-first dispatch; 1 barrier/step.
__global__ __launch_bounds__(256, 4) void attn(
        const _Float16* __restrict__ Qg, const _Float16* __restrict__ Kg,
        const _Float16* __restrict__ Vg,
        _Float16* __restrict__ Op, float* __restrict__ LSEp) {
    __shared__ __align__(16) char smem[20480];

    // decode (QT, ci) from reversed blockIdx.x in [0,40): heavy groups first
    int id = 39 - (int)blockIdx.x;
    int QT, ci;
    if (id < 4)       { QT = id;              ci = 0; }
    else if (id < 12) { int r = id - 4;  QT = 4  + (r >> 1); ci = r & 1; }
    else if (id < 24) { int r = id - 12; int q3 = r / 3; QT = 8 + q3; ci = r - 3 * q3; }
    else              { int r = id - 24; QT = 12 + (r >> 2); ci = r & 3; }
    const int w = blockIdx.y, b = blockIdx.z;
    const int base = win_base(w), stride = win_stride(w);
    const int g = QT >> 2;
    const int cb = 2 * g * (g + 1) + (QT & 3) * (g + 1);
    const int outblk = (b * NW + w) * NBLK2 + cb + ci;
    const int kt0 = ci * 16;                 // 32-col steps
    const int ktmax = 4 * QT + 4;
    const int kt1 = (kt0 + 16 < ktmax) ? kt0 + 16 : ktmax;

    const _Float16* Qb = Qg + (size_t)b * NSEQ * 64;
    const _Float16* Kb = Kg + (size_t)b * NSEQ * 64;
    const _Float16* Vb = Vg + (size_t)b * NSEQ * 64;

    const int t = threadIdx.x;
    const int wid = t >> 6, lane = t & 63, l15 = lane & 15, quad = lane >> 4;

    // K staging: thread stages row sr (0..31), 16B chunk sch (XOR swizzle)
    const int sr = t >> 3, sch = t & 7;
    // V staging: thread (c4 = cols 4c4.., kq = k-pair row)
    const int c4 = t & 15, kq = t >> 4;      // kq in 0..15
    const int vd0 = 4 * c4;

    // Q A-frags for both strips, load once (A[m=l15][k=quad*8+j])
    const size_t qr0 = (size_t)(base + stride * (QT * 128 + 16 * wid + l15)) * 64;
    const size_t qr1 = (size_t)(base + stride * (QT * 128 + 64 + 16 * wid + l15)) * 64;
    const half8 qa00 = *(const half8*)(Qb + qr0 + quad * 8);
    const half8 qa01 = *(const half8*)(Qb + qr0 + 32 + quad * 8);
    const half8 qa10 = *(const half8*)(Qb + qr1 + quad * 8);
    const half8 qa11 = *(const half8*)(Qb + qr1 + 32 + quad * 8);

    f32x4 oacc0[4], oacc1[4];
    float l_[8];
#pragma unroll
    for (int ns = 0; ns < 4; ++ns) {
        oacc0[ns] = (f32x4){0.f, 0.f, 0.f, 0.f};
        oacc1[ns] = (f32x4){0.f, 0.f, 0.f, 0.f};
    }
#pragma unroll
    for (int j = 0; j < 8; ++j) l_[j] = 0.f;

    half8 pk;
    u16x4 pv0, pv1;

    // ---- prologue: stage step kt0 into buffer 0 ----
    {
        const size_t ka = (size_t)(base + stride * (kt0 * 32 + sr)) * 64 + sch * 8;
        pk = *(const half8*)(Kb + ka);
        const size_t va = (size_t)(base + stride * (kt0 * 32 + kq)) * 64 + vd0;
        pv0 = *(const u16x4*)(Vb + va);
        pv1 = *(const u16x4*)(Vb + va + (size_t)stride * 16 * 64);
        char* Kd = smem + K_OFF;
        char* Vd = smem + VT_OFF;
        *(half8*)(Kd + sr * 128 + ((sch ^ (sr & 7)) * 16)) = pk;
#pragma unroll
        for (int i = 0; i < 4; ++i) {
            int d = vd0 + i;
            unsigned int pkw = (unsigned int)pv0[i] | ((unsigned int)pv1[i] << 16);
            int ch = ((kq >> 2) ^ (d & 3) ^ ((d >> 2) & 3)) & 3;
            *(unsigned int*)(Vd + d * 64 + ch * 16 + (kq & 3) * 4) = pkw;
        }
    }

    int cur = 0;
    for (int kt = kt0; kt < kt1; ++kt) {
        __syncthreads();   // buf[cur] visible; all reads of buf[cur^1] done
        const bool pf = (kt + 1 < kt1);
        if (pf) {   // prefetch next step (consumed at end of this iteration)
            const size_t ka = (size_t)(base + stride * ((kt + 1) * 32 + sr)) * 64 + sch * 8;
            pk = *(const half8*)(Kb + ka);
            const size_t va = (size_t)(base + stride * ((kt + 1) * 32 + kq)) * 64 + vd0;
            pv0 = *(const u16x4*)(Vb + va);
            pv1 = *(const u16x4*)(Vb + va + (size_t)stride * 16 * 64);
        }

        const char* Kd = smem + K_OFF + cur * 4096;
        const char* Vd = smem + VT_OFF + cur * 4096;
        char* PsB = smem + PS_OFF;

        // ---- QK^T: K B-frags read ONCE, used by both strips ----
        half8 kb[2][2];
#pragma unroll
        for (int ns = 0; ns < 2; ++ns) {
            const int krow = ns * 16 + l15, swk = krow & 7;
            kb[ns][0] = *(const half8*)(Kd + krow * 128 + ((quad ^ swk) * 16));
            kb[ns][1] = *(const half8*)(Kd + krow * 128 + (((quad + 4) ^ swk) * 16));
        }
        f32x4 sa0[2], sa1[2];
#pragma unroll
        for (int ns = 0; ns < 2; ++ns) {
            f32x4 c0 = (f32x4){0.f, 0.f, 0.f, 0.f};
            c0 = __builtin_amdgcn_mfma_f32_16x16x32_f16(qa00, kb[ns][0], c0, 0, 0, 0);
            c0 = __builtin_amdgcn_mfma_f32_16x16x32_f16(qa01, kb[ns][1], c0, 0, 0, 0);
            sa0[ns] = c0;
            f32x4 c1 = (f32x4){0.f, 0.f, 0.f, 0.f};
            c1 = __builtin_amdgcn_mfma_f32_16x16x32_f16(qa10, kb[ns][0], c1, 0, 0, 0);
            c1 = __builtin_amdgcn_mfma_f32_16x16x32_f16(qa11, kb[ns][1], c1, 0, 0, 0);
            sa1[ns] = c1;
        }
        if (kt >= 4 * QT) {   // causal region (last 4 steps of the tile)
            const int colb = kt * 32 + l15;
            const int row0 = QT * 128 + 16 * wid + quad * 4;
#pragma unroll
            for (int ns = 0; ns < 2; ++ns)
#pragma unroll
                for (int j = 0; j < 4; ++j) {
                    if (colb + ns * 16 > row0 + j)      sa0[ns][j] = -1e30f;
                    if (colb + ns * 16 > row0 + 64 + j) sa1[ns][j] = -1e30f;
                }
        }

        // ---- Vt B-frags read ONCE, reused by both strips' PV ----
        half8 vb[4];
#pragma unroll
        for (int ns = 0; ns < 4; ++ns) {
            const int d = ns * 16 + l15;
            const int ch = (quad ^ (d & 3) ^ ((d >> 2) & 3)) & 3;
            vb[ns] = *(const half8*)(Vd + d * 64 + ch * 16);
        }

        // ---- strip0: exp2 + P write (pair-pack + chunk-XOR) + PV ----
#pragma unroll
        for (int j = 0; j < 4; ++j) {
            const int q = 16 * wid + quad * 4 + j;
            float p0 = EXP2(sa0[0][j] - PBIAS);
            float p1 = EXP2(sa0[1][j] - PBIAS);
            l_[j] += p0 + p1;
            union { fp16x2 h; unsigned int u; } pw;
            pw.h = __builtin_amdgcn_cvt_pkrtz(p0, p1);
            const int ch = ((l15 >> 2) ^ (q & 3) ^ ((q >> 2) & 3)) & 3;
            *(unsigned int*)(PsB + q * 64 + ch * 16 + (l15 & 3) * 4) = pw.u;
        }
        {
            const int qp = 16 * wid + l15;
            const int ch = (quad ^ (qp & 3) ^ ((qp >> 2) & 3)) & 3;
            half8 pa = *(const half8*)(PsB + qp * 64 + ch * 16);
#pragma unroll
            for (int ns = 0; ns < 4; ++ns)
                oacc0[ns] = __builtin_amdgcn_mfma_f32_16x16x32_f16(pa, vb[ns], oacc0[ns], 0, 0, 0);
        }

        // ---- strip1: same Ps rows (same-wave DS ordering => safe) ----
#pragma unroll
        for (int j = 0; j < 4; ++j) {
            const int q = 16 * wid + quad * 4 + j;
            float p0 = EXP2(sa1[0][j] - PBIAS);
            float p1 = EXP2(sa1[1][j] - PBIAS);
            l_[4 + j] += p0 + p1;
            union { fp16x2 h; unsigned int u; } pw;
            pw.h = __builtin_amdgcn_cvt_pkrtz(p0, p1);
            const int ch = ((l15 >> 2) ^ (q & 3) ^ ((q >> 2) & 3)) & 3;
            *(unsigned int*)(PsB + q * 64 + ch * 16 + (l15 & 3) * 4) = pw.u;
        }
        {
            const int qp = 16 * wid + l15;
            const int ch = (quad ^ (qp & 3) ^ ((qp >> 2) & 3)) & 3;
            half8 pa = *(const half8*)(PsB + qp * 64 + ch * 16);
#pragma unroll
            for (int ns = 0; ns < 4; ++ns)
                oacc1[ns] = __builtin_amdgcn_mfma_f32_16x16x32_f16(pa, vb[ns], oacc1[ns], 0, 0, 0);
        }

        // ---- write prefetched step into the other buffer ----
        if (pf) {
            char* Kn = smem + K_OFF + (cur ^ 1) * 4096;
            char* Vn = smem + VT_OFF + (cur ^ 1) * 4096;
            *(half8*)(Kn + sr * 128 + ((sch ^ (sr & 7)) * 16)) = pk;
#pragma unroll
            for (int i = 0; i < 4; ++i) {
                int d = vd0 + i;
                unsigned int pkw = (unsigned int)pv0[i] | ((unsigned int)pv1[i] << 16);
                int ch = ((kq >> 2) ^ (d & 3) ^ ((d >> 2) & 3)) & 3;
                *(unsigned int*)(Vn + d * 64 + ch * 16 + (kq & 3) * 4) = pkw;
            }
        }
        cur ^= 1;
    }

    // ---- epilogue: reduce l, store O (f16) and lse per strip ----
#pragma unroll
    for (int j = 0; j < 8; ++j) {
        float s = l_[j];
        s += __shfl_xor(s, 1, 16);
        s += __shfl_xor(s, 2, 16);
        s += __shfl_xor(s, 4, 16);
        s += __shfl_xor(s, 8, 16);
        l_[j] = s;
    }
    const int qrow0 = 16 * wid + quad * 4;
    if (l15 == 0) {
#pragma unroll
        for (int j = 0; j < 4; ++j) {
            LSEp[(size_t)outblk * 128 + qrow0 + j]      = __logf(l_[j]);
            LSEp[(size_t)outblk * 128 + 64 + qrow0 + j] = __logf(l_[4 + j]);
        }
    }
#pragma unroll
    for (int j = 0; j < 4; ++j) {
        const float inv0 = 1.0f / l_[j];
        const float inv1 = 1.0f / l_[4 + j];
        const size_t r0off = ((size_t)outblk * 128 + qrow0 + j) * 64 + l15;
        const size_t r1off = ((size_t)outblk * 128 + 64 + qrow0 + j) * 64 + l15;
#pragma unroll
        for (int ns = 0; ns < 4; ++ns) {
            Op[r0off + ns * 16] = (_Float16)(oacc0[ns][j] * inv0);
            Op[r1off + ns * 16] = (_Float16)(oacc1[ns][j] * inv1);
        }
    }
}

// ---------------- kernel 3: merge all (window, chunk) partials ------------
typedef _Float16 half8v __attribute__((ext_vector_type(8)));
__global__ __launch_bounds__(256) void mix_out(
        const _Float16* __restrict__ Op, const float* __restrict__ LSEp,
        float* __restrict__ out) {
    int gid = blockIdx.x * 256 + threadIdx.x;   // [0, 4*8192*8)
    int f8 = gid & 7;
    int tpos = (gid >> 3) & (NSEQ - 1);
    int b = gid >> 16;

    int idxs[12];
    float lse[12];
    int nref = 0;
    {   // window of stride 1
        int w = tpos >> 11, j = tpos & (M - 1);
        int QT = j >> 7, gg = QT >> 2, q = j & 127;
        int cbase = 2 * gg * (gg + 1) + (QT & 3) * (gg + 1);
        int bb = ((b * NW + w) * NBLK2 + cbase) * 128 + q;
        int cmax = j >> 9;
        for (int c = 0; c <= cmax; ++c) { idxs[nref] = bb + c * 128; lse[nref] = LSEp[idxs[nref]]; ++nref; }
    }
    if (!(tpos & 1)) {   // stride 2
        int w = 4 + (tpos >> 12), j = (tpos & 4095) >> 1;
        int QT = j >> 7, gg = QT >> 2, q = j & 127;
        int cbase = 2 * gg * (gg + 1) + (QT & 3) * (gg + 1);
        int bb = ((b * NW + w) * NBLK2 + cbase) * 128 + q;
        int cmax = j >> 9;
        for (int c = 0; c <= cmax; ++c) { idxs[nref] = bb + c * 128; lse[nref] = LSEp[idxs[nref]]; ++nref; }
    }
    if (!(tpos & 3)) {   // stride 4
        int j = tpos >> 2;
        int QT = j >> 7, gg = QT >> 2, q = j & 127;
        int cbase = 2 * gg * (gg + 1) + (QT & 3) * (gg + 1);
        int bb = ((b * NW + 6) * NBLK2 + cbase) * 128 + q;
        int cmax = j >> 9;
        for (int c = 0; c <= cmax; ++c) { idxs[nref] = bb + c * 128; lse[nref] = LSEp[idxs[nref]]; ++nref; }
    }

    float Mx = -1e30f;
    for (int i = 0; i < nref; ++i) Mx = fmaxf(Mx, lse[i]);
    float acc[8];
#pragma unroll
    for (int k = 0; k < 8; ++k) acc[k] = 0.f;
    float wsum = 0.f;
    for (int i = 0; i < nref; ++i) {
        float a = __expf(lse[i] - Mx);
        wsum += a;
        half8v v = *(const half8v*)(Op + (size_t)idxs[i] * 64 + f8 * 8);
#pragma unroll
        for (int k = 0; k < 8; ++k) acc[k] += a * (float)v[k];
    }
    float inv = 1.0f / wsum;
    size_t o = ((size_t)b * NSEQ + tpos) * 64 + f8 * 8;
    float4 r0 = make_float4(acc[0] * inv, acc[1] * inv, acc[2] * inv, acc[3] * inv);
    float4 r1 = make_float4(acc[4] * inv, acc[5] * inv, acc[6] * inv, acc[7] * inv);
    *(float4*)&out[o] = r0;
    *(float4*)&out[o + 4] = r1;
}

extern "C" void kernel_launch(void* const* d_in, const int* in_sizes, int n_in,
                              void* d_out, int out_size, void* d_ws, size_t ws_size,
                              hipStream_t stream) {
    const float* x  = (const float*)d_in[0];
    const float* Wq = (const float*)d_in[1];
    const float* Wk = (const float*)d_in[2];
    const float* Wv = (const float*)d_in[3];
    float* out = (float*)d_out;

    const size_t QN = (size_t)NB * NSEQ * CDIM;     // 2,097,152
    _Float16* Qg = (_Float16*)d_ws;
    _Float16* Kg = Qg + QN;
    _Float16* Vg = Kg + QN;
    _Float16* Op = Vg + QN;                         // [b][w][40][128][64] f16
    float* LSEp  = (float*)(Op + (size_t)NB * NW * NBLK2 * 128 * 64);

    qkv_proj<<<NB * NSEQ / 128, 256, 0, stream>>>(x, Wq, Wk, Wv, Qg, Kg, Vg);
    attn<<<dim3(NBLK2, NW, NB), 256, 0, stream>>>(Qg, Kg, Vg, Op, LSEp);
    mix_out<<<(NB * NSEQ * 8) / 256, 256, 0, stream>>>(Op, LSEp, out);
}